// Round 6
// baseline (161.709 us; speedup 1.0000x reference)
//
#include <hip/hip_runtime.h>
#include <math.h>

#define B_N    8192
#define D_DIM  192
#define C_CLS  1024
#define MARGIN 0.2f
#define EPS_T  1e-6f

#define TI     128
#define TJ     128
#define JSPLIT 4
#define JLEN   (B_N / JSPLIT)   // 2048
#define NT     (JLEN / TJ)      // 16 tiles per block
#define RB     384              // bytes per LDS row (linear 192 bf16, required by global_load_lds)

typedef short v8s  __attribute__((ext_vector_type(8)));
typedef float v16f __attribute__((ext_vector_type(16)));

typedef __attribute__((address_space(3))) unsigned int       lds_u32;
typedef __attribute__((address_space(1))) const unsigned int glb_u32;

__device__ __forceinline__ void gll16(const void* g, void* l) {
  __builtin_amdgcn_global_load_lds((glb_u32*)g, (lds_u32*)l, 16, 0, 0);
}

// XOR swizzle: physical byte for logical (row r, col-byte cb). Bijective involution
// within each 384-B row; 16B-aligned cb stays 16B-aligned.
__device__ __forceinline__ int swzb(int r, int cb) {
  return r * RB + (cb ^ ((r & 7) << 4));
}

// stage one 128-row x 384-B tile: 3072 16-B chunks, 6 per thread (512 threads).
// Exactly 6 VMEM instructions per wave -> vmcnt bookkeeping unit for the pipeline.
__device__ __forceinline__ void stage_tile(char* dst, const char* src, int tid) {
  #pragma unroll
  for (int k = 0; k < 6; ++k) {
    int c  = k * 512 + tid;
    int r  = c / 24;
    int cb = (c - r * 24) * 16;
    gll16(src + r * RB + (cb ^ ((r & 7) << 4)),
          dst + (k * 512 + (tid & ~63)) * 16);
  }
}

__device__ __forceinline__ unsigned fkey(float f) {
  unsigned u = __float_as_uint(f);
  return (u & 0x80000000u) ? ~u : (u | 0x80000000u);
}

__device__ __forceinline__ unsigned short to_bf(float x) {
  unsigned u = __float_as_uint(x);
  u += 0x7fffu + ((u >> 16) & 1u);
  return (unsigned short)(u >> 16);
}

// ---------------- prep: cvt fp32->bf16, sq = ||e||^2, init ws ----------------
__global__ __launch_bounds__(256) void prep_kernel(
    const float* __restrict__ e, unsigned short* __restrict__ ebf,
    float* __restrict__ sq,
    unsigned long long* __restrict__ posw, unsigned long long* __restrict__ negw,
    float* __restrict__ accum) {
  int w = threadIdx.x >> 6, lane = threadIdx.x & 63;
  int row = blockIdx.x * 4 + w;
  const float* p = e + (size_t)row * D_DIM;
  float v0 = p[lane], v1 = p[lane + 64], v2 = p[lane + 128];
  unsigned short* q = ebf + (size_t)row * D_DIM;
  q[lane] = to_bf(v0); q[lane + 64] = to_bf(v1); q[lane + 128] = to_bf(v2);
  float s = v0 * v0 + v1 * v1 + v2 * v2;
  #pragma unroll
  for (int off = 32; off; off >>= 1) s += __shfl_xor(s, off);
  if (lane == 0) sq[row] = s;
  int b = blockIdx.x;
  if (b < 32)       posw[b * 256 + threadIdx.x] = 0ULL;
  else if (b < 64)  negw[(b - 32) * 256 + threadIdx.x] = ~0ULL;
  else if (b == 64 && threadIdx.x < 4) ((unsigned*)accum)[threadIdx.x] = 0u;
}

// ---------------- hard mining: counted-vmcnt pipeline (T4) + fused CE ----------------
// 512 threads = 8 waves: wave w -> j-band wj = w&3, i-half wi = w>>2.
// Main loop per tile t:
//   s_waitcnt vmcnt(6)   -> own tile-t loads landed (tile t+1's 6 stay in flight)
//   s_barrier (raw)      -> all waves' tile-t loads landed; NO vmcnt(0) drain
//   compute tile t       -> ds_read+MFMA+mining epilogue (lgkmcnt compiler-managed)
//   s_barrier (raw)      -> all reads of buf[t&1] serviced
//   stage tile t+2 into buf[t&1]
// sq/tgt for the whole 2048-row j-span staged ONCE in prologue (keeps loop at
// exactly 6 VMEM ops/wave/tile so the counted vmcnt is well-defined).
__global__ __launch_bounds__(512, 1) void mine_kernel(
    const unsigned short* __restrict__ ebf, const int* __restrict__ tgt,
    const float* __restrict__ sq, const float* __restrict__ logits,
    unsigned long long* __restrict__ posw, unsigned long long* __restrict__ negw,
    float* __restrict__ accum) {
  __shared__ unsigned short buf[2][TJ * (RB / 2)];   // 2 x 49152 B
  __shared__ float lds_sq[JLEN];                     // 8192 B
  __shared__ int   lds_tg[JLEN];                     // 8192 B
  __shared__ unsigned long long pmrg[TI];
  __shared__ unsigned long long nmrg[TI];
  __shared__ float ce_part[8];

  const int tid  = threadIdx.x;
  const int w    = tid >> 6;
  const int lane = tid & 63;
  const int n5   = lane & 31;
  const int h    = lane >> 5;
  const int wj   = w & 3;      // j-band within tile
  const int wi   = w >> 2;     // i-half
  const int i0 = blockIdx.x * TI;
  const int jb = blockIdx.y * JLEN;

  char* bufA = (char*)buf[0];
  char* bufB = (char*)buf[1];

  if (tid < TI) { pmrg[tid] = 0ULL; nmrg[tid] = ~0ULL; }

  int my_t[2];
  #pragma unroll
  for (int tb = 0; tb < 2; ++tb) my_t[tb] = tgt[i0 + wi * 64 + tb * 32 + n5];

  // ---- prologue staging (issue order matters for vmcnt accounting) ----
  stage_tile(bufB, (const char*)(ebf + (size_t)i0 * D_DIM), tid);   // 6: i-tile
  stage_tile(bufA, (const char*)(ebf + (size_t)jb * D_DIM), tid);   // 6: j-tile 0
  gll16((const char*)(sq  + jb) + tid * 16, (char*)lds_sq + (tid & ~63) * 16);  // 1
  gll16((const char*)(tgt + jb) + tid * 16, (char*)lds_tg + (tid & ~63) * 16);  // 1
  // wait: i-tile done (oldest 6); leave tile0's 6 + sq/tgt's 2 in flight
  asm volatile("s_waitcnt vmcnt(8)" ::: "memory");
  __builtin_amdgcn_s_barrier();
  __builtin_amdgcn_sched_barrier(0);

  v8s bfrag[2][12];
  #pragma unroll
  for (int tb = 0; tb < 2; ++tb)
    #pragma unroll
    for (int kc = 0; kc < 12; ++kc)
      bfrag[tb][kc] = *(const v8s*)(bufB + swzb(wi * 64 + tb * 32 + n5, kc * 32 + h * 16));

  // all bfrag ds_reads serviced before buf[1] is overwritten by tile 1
  asm volatile("s_waitcnt lgkmcnt(0)" ::: "memory");
  __builtin_amdgcn_s_barrier();

  stage_tile(bufB, (const char*)(ebf + (size_t)(jb + TJ) * D_DIM), tid);  // 6: j-tile 1

  float    pv[2] = {-3.4e38f, -3.4e38f}, nv[2] = {3.4e38f, 3.4e38f};
  unsigned pi_[2] = {0u, 0u}, ni_[2] = {0xFFFFFFFFu, 0xFFFFFFFFu};

  for (int t = 0; t < NT; ++t) {
    char* cbuf = (t & 1) ? bufB : bufA;

    // head: own tile-t loads done (t=0 also retires sq/tgt), next tile stays in flight
    if (t < NT - 1) asm volatile("s_waitcnt vmcnt(6)" ::: "memory");
    else            asm volatile("s_waitcnt vmcnt(0)" ::: "memory");
    __builtin_amdgcn_s_barrier();
    __builtin_amdgcn_sched_barrier(0);

    v16f acc[2];
    #pragma unroll
    for (int tb = 0; tb < 2; ++tb)
      #pragma unroll
      for (int r = 0; r < 16; ++r) acc[tb][r] = 0.f;

    __builtin_amdgcn_s_setprio(1);
    #pragma unroll
    for (int kc = 0; kc < 12; ++kc) {
      v8s afr = *(const v8s*)(cbuf + swzb(wj * 32 + n5, kc * 32 + h * 16));
      acc[0] = __builtin_amdgcn_mfma_f32_32x32x16_bf16(afr, bfrag[0][kc], acc[0], 0, 0, 0);
      acc[1] = __builtin_amdgcn_mfma_f32_32x32x16_bf16(afr, bfrag[1][kc], acc[1], 0, 0, 0);
    }
    __builtin_amdgcn_s_setprio(0);

    // epilogue: j = wj*32 + q + 8p + 4h ; i = wi*64 + tb*32 + (lane&31)
    const int j0 = jb + t * TJ;
    const int jt = t * TJ;
    #pragma unroll
    for (int p = 0; p < 4; ++p) {
      int jb4 = wj * 32 + p * 8 + h * 4;
      float4 s4 = *(const float4*)&lds_sq[jt + jb4];
      int4   t4 = *(const int4*)&lds_tg[jt + jb4];
      #pragma unroll
      for (int q = 0; q < 4; ++q) {
        float sv = (q == 0) ? s4.x : (q == 1) ? s4.y : (q == 2) ? s4.z : s4.w;
        int   tv = (q == 0) ? t4.x : (q == 1) ? t4.y : (q == 2) ? t4.z : t4.w;
        unsigned jg = (unsigned)(j0 + jb4 + q);
        #pragma unroll
        for (int tb = 0; tb < 2; ++tb) {
          float val = fmaf(acc[tb][p * 4 + q], -2.0f, sv);
          bool same = (tv == my_t[tb]);
          if (same && val > pv[tb])  { pv[tb] = val; pi_[tb] = jg; }
          if (!same && val < nv[tb]) { nv[tb] = val; ni_[tb] = jg; }
        }
      }
    }

    // all reads of cbuf serviced (values consumed above) -> safe to re-stage
    __builtin_amdgcn_s_barrier();
    if (t + 2 < NT)
      stage_tile(cbuf, (const char*)(ebf + (size_t)(jb + (t + 2) * TJ) * D_DIM), tid);
  }

  __syncthreads();   // full drain before merge phase

  // ---- merge: h-partner lanes (shfl), then 8 waves via LDS atomics, then global ----
  #pragma unroll
  for (int tb = 0; tb < 2; ++tb) {
    unsigned long long pk =
        ((unsigned long long)fkey(pv[tb]) << 32) | (unsigned long long)(unsigned)(~pi_[tb]);
    unsigned long long nk =
        ((unsigned long long)fkey(nv[tb]) << 32) | (unsigned long long)ni_[tb];
    unsigned long long po = __shfl_xor(pk, 32);
    unsigned long long no = __shfl_xor(nk, 32);
    pk = pk > po ? pk : po;
    nk = nk < no ? nk : no;
    if (h == 0) {
      atomicMax(&pmrg[wi * 64 + tb * 32 + n5], pk);
      atomicMin(&nmrg[wi * 64 + tb * 32 + n5], nk);
    }
  }
  __syncthreads();
  if (tid < TI) {
    atomicMax(&posw[i0 + tid], pmrg[tid]);
    atomicMin(&negw[i0 + tid], nmrg[tid]);
  }

  // ---- fused cross-entropy: 32 logits rows per block (4 per wave) ----
  {
    int blin = blockIdx.y * 64 + blockIdx.x;   // 0..255
    float ce_acc = 0.f;
    #pragma unroll
    for (int it = 0; it < 4; ++it) {
      int row = blin * 32 + w * 4 + it;
      const float* lp = logits + (size_t)row * C_CLS;
      float4 x[4];
      #pragma unroll
      for (int u = 0; u < 4; ++u) x[u] = *(const float4*)(lp + lane * 4 + 256 * u);
      float m = -3.4e38f;
      #pragma unroll
      for (int u = 0; u < 4; ++u)
        m = fmaxf(m, fmaxf(fmaxf(x[u].x, x[u].y), fmaxf(x[u].z, x[u].w)));
      #pragma unroll
      for (int off = 32; off; off >>= 1) m = fmaxf(m, __shfl_xor(m, off));
      float s = 0.f;
      #pragma unroll
      for (int u = 0; u < 4; ++u)
        s += __expf(x[u].x - m) + __expf(x[u].y - m) +
             __expf(x[u].z - m) + __expf(x[u].w - m);
      #pragma unroll
      for (int off = 32; off; off >>= 1) s += __shfl_xor(s, off);
      if (lane == 0) ce_acc += m + __logf(s) - lp[tgt[row]];
    }
    if (lane == 0) ce_part[w] = ce_acc;
  }
  __syncthreads();
  if (tid == 0) {
    float a = 0.f;
    #pragma unroll
    for (int k = 0; k < 8; ++k) a += ce_part[k];
    atomicAdd(&accum[0], a);
  }
}

// ---------------- triplet loss on mined indices + last-block finalize ----------------
__global__ __launch_bounds__(1024) void trip_fin_kernel(
    const float* __restrict__ e,
    const unsigned long long* __restrict__ posw,
    const unsigned long long* __restrict__ negw,
    float* __restrict__ accum, float* __restrict__ out) {
  __shared__ float ssum[16];
  __shared__ float scnt[16];
  int w = threadIdx.x >> 6, lane = threadIdx.x & 63;
  int i = blockIdx.x * 16 + w;
  unsigned long long pp = posw[i], np = negw[i];
  unsigned pidx = ~(unsigned)pp;
  unsigned nidx = (unsigned)np;
  float res = 0.f, c = 0.f;
  // pidx == i means self won the argmax => no real positive => invalid row
  if (pp != 0ULL && np != ~0ULL && pidx != (unsigned)i) {
    const float* pa = e + (size_t)i * D_DIM;
    const float* pb = e + (size_t)pidx * D_DIM;
    const float* pc = e + (size_t)nidx * D_DIM;
    float dap = 0.f, dan = 0.f;
    #pragma unroll
    for (int t = 0; t < 3; ++t) {
      int k = lane + 64 * t;
      float av = pa[k];
      float d1 = av - pb[k] + EPS_T;
      float d2 = av - pc[k] + EPS_T;
      dap += d1 * d1;
      dan += d2 * d2;
    }
    #pragma unroll
    for (int off = 32; off; off >>= 1) {
      dap += __shfl_xor(dap, off);
      dan += __shfl_xor(dan, off);
    }
    res = fmaxf(sqrtf(dap) - sqrtf(dan) + MARGIN, 0.f);
    c = 1.f;
  }
  if (lane == 0) { ssum[w] = res; scnt[w] = c; }
  __syncthreads();
  if (threadIdx.x == 0) {
    float a = 0.f, b = 0.f;
    #pragma unroll
    for (int k = 0; k < 16; ++k) { a += ssum[k]; b += scnt[k]; }
    atomicAdd(&accum[1], a);
    atomicAdd(&accum[2], b);
    __threadfence();
    unsigned old = atomicAdd((unsigned*)&accum[3], 1u);
    if (old == 511u) {
      __threadfence();
      float cls = atomicAdd(&accum[0], 0.f);   // coherent reads via atomics
      float ts  = atomicAdd(&accum[1], 0.f);
      float tc  = atomicAdd(&accum[2], 0.f);
      float trip = (tc > 0.f) ? ts / fmaxf(tc, 1.f) : 0.f;
      out[0] = cls / (float)B_N + trip;
    }
  }
}

extern "C" void kernel_launch(void* const* d_in, const int* in_sizes, int n_in,
                              void* d_out, int out_size, void* d_ws, size_t ws_size,
                              hipStream_t stream) {
  const float* emb    = (const float*)d_in[0];
  const float* logits = (const float*)d_in[1];
  const int*   tgt    = (const int*)d_in[2];
  float* out = (float*)d_out;

  char* ws = (char*)d_ws;
  unsigned short* ebf = (unsigned short*)ws;                          // 3,145,728 B
  unsigned long long* posw = (unsigned long long*)(ws + 3145728);     // 65536 B
  unsigned long long* negw = (unsigned long long*)(ws + 3145728 + 65536);
  float* sq    = (float*)(ws + 3145728 + 131072);                     // 32768 B
  float* accum = (float*)(ws + 3145728 + 163840);                     // 16 B: cls,tsum,tcnt,counter

  prep_kernel<<<2048, 256, 0, stream>>>(emb, ebf, sq, posw, negw, accum);
  mine_kernel<<<dim3(B_N / TI, JSPLIT), 512, 0, stream>>>(ebf, tgt, sq, logits, posw, negw, accum);
  trip_fin_kernel<<<512, 1024, 0, stream>>>(emb, posw, negw, accum, out);
}

// Round 8
// 157.061 us; speedup vs baseline: 1.0296x; 1.0296x over previous
//
#include <hip/hip_runtime.h>
#include <math.h>

#define B_N    8192
#define D_DIM  192
#define C_CLS  1024
#define MARGIN 0.2f
#define EPS_T  1e-6f

#define TI     128
#define TJ     128
#define JSPLIT 8
#define JLEN   (B_N / JSPLIT)   // 1024
#define NT     (JLEN / TJ)      // 8 tiles per block
#define RB     512              // LDS row stride in bytes: 32 x 16B slots (24 used)

typedef short v8s  __attribute__((ext_vector_type(8)));
typedef float v16f __attribute__((ext_vector_type(16)));

typedef __attribute__((address_space(3))) unsigned int       lds_u32;
typedef __attribute__((address_space(1))) const unsigned int glb_u32;

__device__ __forceinline__ void gll16(const void* g, void* l) {
  __builtin_amdgcn_global_load_lds((glb_u32*)g, (lds_u32*)l, 16, 0, 0);
}

// Swizzle: logical (row r, 16B-slot s) lives at physical slot s^(r&31).
// 32 lanes reading rows r..r+31 at the same logical slot hit 32 DISTINCT
// physical slots -> zero bank conflicts on ds_read_b128.
__device__ __forceinline__ int swz(int r, int s) {
  return r * RB + ((s ^ (r & 31)) << 4);
}

// Stage one 128-row tile: linear LDS dest (global_load_lds rule), source
// carries the inverse swizzle. 4096 chunks, 16/thread @256 threads.
// Physical slot p of row r holds logical slot s = p^(r&31); s>=24 are
// dummy slots (read row base; never read back).
__device__ __forceinline__ void stage_tile(char* dst, const char* src, int tid) {
  #pragma unroll
  for (int k = 0; k < 16; ++k) {
    int c = k * 256 + tid;
    int r = c >> 5;
    int s = (c & 31) ^ (r & 31);
    int so = (s < 24) ? (s << 4) : 0;
    gll16(src + r * 384 + so, dst + (k * 256 + (tid & ~63)) * 16);
  }
}

__device__ __forceinline__ unsigned fkey(float f) {
  unsigned u = __float_as_uint(f);
  return (u & 0x80000000u) ? ~u : (u | 0x80000000u);
}

__device__ __forceinline__ unsigned short to_bf(float x) {
  unsigned u = __float_as_uint(x);
  u += 0x7fffu + ((u >> 16) & 1u);
  return (unsigned short)(u >> 16);
}

// ---------------- prep: cvt fp32->bf16, sq = ||e||^2, init ws ----------------
__global__ __launch_bounds__(256) void prep_kernel(
    const float* __restrict__ e, unsigned short* __restrict__ ebf,
    float* __restrict__ sq,
    unsigned long long* __restrict__ posw, unsigned long long* __restrict__ negw,
    float* __restrict__ accum) {
  int w = threadIdx.x >> 6, lane = threadIdx.x & 63;
  int row = blockIdx.x * 4 + w;
  const float* p = e + (size_t)row * D_DIM;
  float v0 = p[lane], v1 = p[lane + 64], v2 = p[lane + 128];
  unsigned short* q = ebf + (size_t)row * D_DIM;
  q[lane] = to_bf(v0); q[lane + 64] = to_bf(v1); q[lane + 128] = to_bf(v2);
  float s = v0 * v0 + v1 * v1 + v2 * v2;
  #pragma unroll
  for (int off = 32; off; off >>= 1) s += __shfl_xor(s, off);
  if (lane == 0) sq[row] = s;
  int b = blockIdx.x;
  if (b < 32)       posw[b * 256 + threadIdx.x] = 0ULL;
  else if (b < 64)  negw[(b - 32) * 256 + threadIdx.x] = ~0ULL;
  else if (b == 64 && threadIdx.x < 4) ((unsigned*)accum)[threadIdx.x] = 0u;
}

// ---------------- hard mining (R0 layout + gload_lds + conflict-free swizzle) ----------------
// 256 thr = 4 waves: wj = w&1 (j 64-band, ta in {0,1}), wi = w>>1 (i 64-half, tb in {0,1}).
// Per kc: 2 A ds_reads feed 4 MFMAs (A-frag shared across both B-frags).
// Simple 2-barrier loop; 2 independent blocks/CU provide the overlap (R0-proven).
__global__ __launch_bounds__(256, 2) void mine_kernel(
    const unsigned short* __restrict__ ebf, const int* __restrict__ tgt,
    const float* __restrict__ sq, const float* __restrict__ logits,
    unsigned long long* __restrict__ posw, unsigned long long* __restrict__ negw,
    float* __restrict__ accum) {
  __shared__ unsigned short lds_b[TJ * (RB / 2)];   // 65536 B
  __shared__ float lds_sq[JLEN];                    // 4096 B
  __shared__ int   lds_tg[JLEN];                    // 4096 B
  __shared__ float ce_part[4];

  const int tid  = threadIdx.x;
  const int w    = tid >> 6;
  const int lane = tid & 63;
  const int n5   = lane & 31;
  const int h    = lane >> 5;
  const int wj   = w & 1;      // j band (64 rows)
  const int wi   = w >> 1;     // i half (64 cols)
  const int i0 = blockIdx.x * TI;
  const int jb = blockIdx.y * JLEN;

  char* ldsc = (char*)lds_b;

  // ---- prologue: stage i-tile + block's whole sq/tgt span (async) ----
  stage_tile(ldsc, (const char*)(ebf + (size_t)i0 * D_DIM), tid);
  gll16((const char*)(sq  + jb) + tid * 16, (char*)lds_sq + (tid & ~63) * 16);
  gll16((const char*)(tgt + jb) + tid * 16, (char*)lds_tg + (tid & ~63) * 16);

  int my_t[2];
  #pragma unroll
  for (int tb = 0; tb < 2; ++tb) my_t[tb] = tgt[i0 + wi * 64 + tb * 32 + n5];

  __syncthreads();   // i-tile + sq/tgt landed

  v8s bfrag[2][12];
  #pragma unroll
  for (int tb = 0; tb < 2; ++tb)
    #pragma unroll
    for (int kc = 0; kc < 12; ++kc)
      bfrag[tb][kc] = *(const v8s*)(ldsc + swz(wi * 64 + tb * 32 + n5, 2 * kc + h));

  float    pv[2] = {-3.4e38f, -3.4e38f}, nv[2] = {3.4e38f, 3.4e38f};
  unsigned pi_[2] = {0u, 0u}, ni_[2] = {0xFFFFFFFFu, 0xFFFFFFFFu};

  for (int t = 0; t < NT; ++t) {
    __syncthreads();   // all reads of lds_b done -> safe to overwrite
    stage_tile(ldsc, (const char*)(ebf + (size_t)(jb + t * TJ) * D_DIM), tid);
    __syncthreads();   // j-tile landed (compiler drains vmcnt here)

    v16f acc[2][2];
    #pragma unroll
    for (int ta = 0; ta < 2; ++ta)
      #pragma unroll
      for (int tb = 0; tb < 2; ++tb)
        #pragma unroll
        for (int r = 0; r < 16; ++r) acc[ta][tb][r] = 0.f;

    #pragma unroll
    for (int kc = 0; kc < 12; ++kc) {
      v8s afr0 = *(const v8s*)(ldsc + swz(wj * 64 +  0 + n5, 2 * kc + h));
      v8s afr1 = *(const v8s*)(ldsc + swz(wj * 64 + 32 + n5, 2 * kc + h));
      acc[0][0] = __builtin_amdgcn_mfma_f32_32x32x16_bf16(afr0, bfrag[0][kc], acc[0][0], 0, 0, 0);
      acc[0][1] = __builtin_amdgcn_mfma_f32_32x32x16_bf16(afr0, bfrag[1][kc], acc[0][1], 0, 0, 0);
      acc[1][0] = __builtin_amdgcn_mfma_f32_32x32x16_bf16(afr1, bfrag[0][kc], acc[1][0], 0, 0, 0);
      acc[1][1] = __builtin_amdgcn_mfma_f32_32x32x16_bf16(afr1, bfrag[1][kc], acc[1][1], 0, 0, 0);
    }

    // epilogue: j = wj*64 + ta*32 + 8p + 4h + q ; i = wi*64 + tb*32 + n5
    const int j0 = jb + t * TJ;
    const int jt = t * TJ;
    #pragma unroll
    for (int ta = 0; ta < 2; ++ta)
      #pragma unroll
      for (int p = 0; p < 4; ++p) {
        int jb4 = wj * 64 + ta * 32 + p * 8 + h * 4;
        float4 s4 = *(const float4*)&lds_sq[jt + jb4];   // 2 uniq addrs/wave: broadcast
        int4   t4 = *(const int4*)&lds_tg[jt + jb4];
        #pragma unroll
        for (int q = 0; q < 4; ++q) {
          float sv = (q == 0) ? s4.x : (q == 1) ? s4.y : (q == 2) ? s4.z : s4.w;
          int   tv = (q == 0) ? t4.x : (q == 1) ? t4.y : (q == 2) ? t4.z : t4.w;
          unsigned jg = (unsigned)(j0 + jb4 + q);
          #pragma unroll
          for (int tb = 0; tb < 2; ++tb) {
            float val = fmaf(acc[ta][tb][p * 4 + q], -2.0f, sv);
            bool same = (tv == my_t[tb]);
            if (same  && val > pv[tb]) { pv[tb] = val; pi_[tb] = jg; }
            if (!same && val < nv[tb]) { nv[tb] = val; ni_[tb] = jg; }
          }
        }
      }
  }

  // ---- merge: h-partner lanes (same i col), then global packed atomics ----
  #pragma unroll
  for (int tb = 0; tb < 2; ++tb) {
    unsigned long long pk =
        ((unsigned long long)fkey(pv[tb]) << 32) | (unsigned long long)(unsigned)(~pi_[tb]);
    unsigned long long nk =
        ((unsigned long long)fkey(nv[tb]) << 32) | (unsigned long long)ni_[tb];
    unsigned long long po = __shfl_xor(pk, 32);
    unsigned long long no = __shfl_xor(nk, 32);
    pk = pk > po ? pk : po;
    nk = nk < no ? nk : no;
    if (h == 0) {
      int irow = i0 + wi * 64 + tb * 32 + n5;
      atomicMax(&posw[irow], pk);
      atomicMin(&negw[irow], nk);
    }
  }

  // ---- fused cross-entropy: this block handles 16 logits rows ----
  {
    int blin = blockIdx.y * 64 + blockIdx.x;
    float ce_acc = 0.f;
    #pragma unroll
    for (int it = 0; it < 4; ++it) {
      int row = blin * 16 + it * 4 + w;
      const float* lp = logits + (size_t)row * C_CLS;
      float4 x[4];
      #pragma unroll
      for (int u = 0; u < 4; ++u) x[u] = *(const float4*)(lp + lane * 4 + 256 * u);
      float m = -3.4e38f;
      #pragma unroll
      for (int u = 0; u < 4; ++u)
        m = fmaxf(m, fmaxf(fmaxf(x[u].x, x[u].y), fmaxf(x[u].z, x[u].w)));
      #pragma unroll
      for (int off = 32; off; off >>= 1) m = fmaxf(m, __shfl_xor(m, off));
      float s = 0.f;
      #pragma unroll
      for (int u = 0; u < 4; ++u)
        s += __expf(x[u].x - m) + __expf(x[u].y - m) +
             __expf(x[u].z - m) + __expf(x[u].w - m);
      #pragma unroll
      for (int off = 32; off; off >>= 1) s += __shfl_xor(s, off);
      if (lane == 0) ce_acc += m + __logf(s) - lp[tgt[row]];
    }
    if (lane == 0) ce_part[w] = ce_acc;
  }
  __syncthreads();
  if (tid == 0)
    atomicAdd(&accum[0], ce_part[0] + ce_part[1] + ce_part[2] + ce_part[3]);
}

// ---------------- triplet loss on mined indices + last-block finalize ----------------
__global__ __launch_bounds__(1024) void trip_fin_kernel(
    const float* __restrict__ e,
    const unsigned long long* __restrict__ posw,
    const unsigned long long* __restrict__ negw,
    float* __restrict__ accum, float* __restrict__ out) {
  __shared__ float ssum[16];
  __shared__ float scnt[16];
  int w = threadIdx.x >> 6, lane = threadIdx.x & 63;
  int i = blockIdx.x * 16 + w;
  unsigned long long pp = posw[i], np = negw[i];
  unsigned pidx = ~(unsigned)pp;
  unsigned nidx = (unsigned)np;
  float res = 0.f, c = 0.f;
  // pidx == i means self won the argmax => no real positive => invalid row
  if (pp != 0ULL && np != ~0ULL && pidx != (unsigned)i) {
    const float* pa = e + (size_t)i * D_DIM;
    const float* pb = e + (size_t)pidx * D_DIM;
    const float* pc = e + (size_t)nidx * D_DIM;
    float dap = 0.f, dan = 0.f;
    #pragma unroll
    for (int t = 0; t < 3; ++t) {
      int k = lane + 64 * t;
      float av = pa[k];
      float d1 = av - pb[k] + EPS_T;
      float d2 = av - pc[k] + EPS_T;
      dap += d1 * d1;
      dan += d2 * d2;
    }
    #pragma unroll
    for (int off = 32; off; off >>= 1) {
      dap += __shfl_xor(dap, off);
      dan += __shfl_xor(dan, off);
    }
    res = fmaxf(sqrtf(dap) - sqrtf(dan) + MARGIN, 0.f);
    c = 1.f;
  }
  if (lane == 0) { ssum[w] = res; scnt[w] = c; }
  __syncthreads();
  if (threadIdx.x == 0) {
    float a = 0.f, b = 0.f;
    #pragma unroll
    for (int k = 0; k < 16; ++k) { a += ssum[k]; b += scnt[k]; }
    atomicAdd(&accum[1], a);
    atomicAdd(&accum[2], b);
    __threadfence();
    unsigned old = atomicAdd((unsigned*)&accum[3], 1u);
    if (old == 511u) {
      __threadfence();
      float cls = atomicAdd(&accum[0], 0.f);   // coherent reads via atomics
      float ts  = atomicAdd(&accum[1], 0.f);
      float tc  = atomicAdd(&accum[2], 0.f);
      float trip = (tc > 0.f) ? ts / fmaxf(tc, 1.f) : 0.f;
      out[0] = cls / (float)B_N + trip;
    }
  }
}

extern "C" void kernel_launch(void* const* d_in, const int* in_sizes, int n_in,
                              void* d_out, int out_size, void* d_ws, size_t ws_size,
                              hipStream_t stream) {
  const float* emb    = (const float*)d_in[0];
  const float* logits = (const float*)d_in[1];
  const int*   tgt    = (const int*)d_in[2];
  float* out = (float*)d_out;

  char* ws = (char*)d_ws;
  unsigned short* ebf = (unsigned short*)ws;                          // 3,145,728 B
  unsigned long long* posw = (unsigned long long*)(ws + 3145728);     // 65536 B
  unsigned long long* negw = (unsigned long long*)(ws + 3145728 + 65536);
  float* sq    = (float*)(ws + 3145728 + 131072);                     // 32768 B
  float* accum = (float*)(ws + 3145728 + 163840);                     // 16 B: cls,tsum,tcnt,counter

  prep_kernel<<<2048, 256, 0, stream>>>(emb, ebf, sq, posw, negw, accum);
  mine_kernel<<<dim3(B_N / TI, JSPLIT), 256, 0, stream>>>(ebf, tgt, sq, logits, posw, negw, accum);
  trip_fin_kernel<<<512, 1024, 0, stream>>>(emb, posw, negw, accum, out);
}